// Round 13
// baseline (134.920 us; speedup 1.0000x reference)
//
#include <hip/hip_runtime.h>
#include <stdint.h>

typedef unsigned long long u64;
typedef __attribute__((ext_vector_type(2))) float v2f;

#define A_TOTAL 43008
#define NB 16
#define NM 128
#define SPLIT 168                 // blocks per batch; 4 waves; 64 anchors/lane-wave
#define WPB 4
#define CPB 8                     // 8 chunks x 8 pairs (16 boxes)

// Bit-exact packed fp32 division via Markstein sequence (scalar version
// R8-proven absmax 0.0; pk ops are IEEE per-half -> identical results).
__device__ __forceinline__ v2f exact_div2(v2f x, v2f y) {
    float r0, r1;
    asm("v_rcp_f32 %0, %1" : "=v"(r0) : "v"(y.x));
    asm("v_rcp_f32 %0, %1" : "=v"(r1) : "v"(y.y));
    v2f r = {r0, r1};
    v2f one = {1.0f, 1.0f};
    v2f e  = __builtin_elementwise_fma(-y, r, one);
    r      = __builtin_elementwise_fma(e, r, r);
    e      = __builtin_elementwise_fma(-y, r, one);
    r      = __builtin_elementwise_fma(e, r, r);
    v2f q  = x * r;
    v2f rs = __builtin_elementwise_fma(-y, q, x);
    return __builtin_elementwise_fma(rs, r, q);
}

// u64 cross-lane DPP max-merge helper (pairs stay inside aligned quads).
__device__ __forceinline__ u64 dpp_u64(u64 v, const int ctrl) {
    int lo = (int)(unsigned)v, hi = (int)(unsigned)(v >> 32);
    int plo, phi;
    if (ctrl == 0xB1) {          // quad_perm [1,0,3,2] : xor 1
        plo = __builtin_amdgcn_update_dpp(lo, lo, 0xB1, 0xF, 0xF, false);
        phi = __builtin_amdgcn_update_dpp(hi, hi, 0xB1, 0xF, 0xF, false);
    } else {                     // quad_perm [2,3,0,1] : xor 2
        plo = __builtin_amdgcn_update_dpp(lo, lo, 0x4E, 0xF, 0xF, false);
        phi = __builtin_amdgcn_update_dpp(hi, hi, 0x4E, 0xF, 0xF, false);
    }
    return ((u64)(unsigned)phi << 32) | (unsigned)plo;
}

// Prep: pair-interleaved box layout [NB][64 pairs][10]:
// {x1_0,x1_1, y1_0,y1_1, x2_0,x2_1, y2_0,y2_1, area_0,area_1}
// so fused can ds_read_b64 a packed VGPR pair per coord. Also zeros colfinal.
__global__ __launch_bounds__(256) void prep_kernel(
    const float4* __restrict__ bboxes, float* __restrict__ pairbox,
    u64* __restrict__ colfinal) {
#pragma clang fp contract(off)
    const int i = blockIdx.x * 256 + threadIdx.x;    // 0..2047 = (b, m)
    const int b = i >> 7, m = i & 127;
    float4 v = bboxes[i];
    const int p = m >> 1, o = m & 1;
    float* dst = pairbox + ((size_t)b * 64 + p) * 10;
    dst[0 + o] = v.x;
    dst[2 + o] = v.y;
    dst[4 + o] = v.z;
    dst[6 + o] = v.w;
    dst[8 + o] = (v.z - v.x) * (v.w - v.y);
    colfinal[i] = 0ull;
}

// ---------------------------------------------------------------------------
// Fused IoU pass (R12 structure, packed-f32 arithmetic): lane = anchor,
// loop = box pair (ascending m -> jnp first-occurrence ties preserved).
// Box pairs arrive packed via uniform-address ds_read_b64 from LDS staging.
// Sub/mul/add/fma chain (incl. Markstein div) runs as v_pk_* ; min/max split
// to scalar (no pk form). Col (per-box): f32 LDS transpose per 16-box chunk,
// 4 lanes/box x 16 serial (ascending anchor, strict '>'), 2 quad-DPP merges,
// per-wave stage, block-merge, device atomicMax. Row: private strict '>'.
// ---------------------------------------------------------------------------
__global__ __launch_bounds__(256) void fused_kernel(
    const float4* __restrict__ anchors, const float* __restrict__ pairbox,
    u64* __restrict__ rowkey,        // [NB][A_TOTAL] (iou_bits<<32)|m
    u64* __restrict__ colfinal) {    // [NB][NM] atomicMax table
#pragma clang fp contract(off)
    const int b = blockIdx.y, tid = threadIdx.x;
    const int lane = tid & 63, wv = tid >> 6;
    const int abase = blockIdx.x * 256 + wv * 64;

    __shared__ float s_col[WPB][16][65];  // 16-box chunk transpose
    __shared__ u64   s_ck[WPB][NM];       // per-wave col keys
    __shared__ float s_pb[640];           // 64 pairs x 10 (pair-interleaved)

    for (int i = tid; i < 640; i += 256)
        s_pb[i] = pairbox[(size_t)b * 640 + i];

    // this lane's anchor, converted once (amortized over 64 pair-iters)
    float4 an = anchors[abase + lane];
    float hw = an.z * 0.5f, hh = an.w * 0.5f;
    float ax1 = an.x - hw, ay1 = an.y - hh;
    float ax2 = an.x + hw, ay2 = an.y + hh;
    float areaA = (ax2 - ax1) * (ay2 - ay1);
    v2f aA = {areaA, areaA};              // loop-invariant packed broadcast

    __syncthreads();

    float best_v = -1.0f; int best_m = 0;             // private row state
    const int bi = lane >> 2, part = lane & 3;        // col reduce: 4 lanes/box
    const int rbase = part * 16;

    for (int c = 0; c < CPB; ++c) {
#pragma unroll
        for (int i = 0; i < 8; ++i) {
            const int p = c * 8 + i;                   // pair index (uniform)
            const float* pb = &s_pb[p * 10];           // 8B-aligned
            v2f bx1 = *(const v2f*)(pb + 0);           // ds_read_b64 broadcast
            v2f by1 = *(const v2f*)(pb + 2);
            v2f bx2 = *(const v2f*)(pb + 4);
            v2f by2 = *(const v2f*)(pb + 6);
            v2f aB  = *(const v2f*)(pb + 8);

            v2f va1 = {ax1, ax1}, vy1 = {ay1, ay1};
            v2f va2 = {ax2, ax2}, vy2 = {ay2, ay2};
            v2f ltx = __builtin_elementwise_max(va1, bx1);
            v2f lty = __builtin_elementwise_max(vy1, by1);
            v2f rbx = __builtin_elementwise_min(va2, bx2);
            v2f rby = __builtin_elementwise_min(vy2, by2);
            v2f zero = {0.0f, 0.0f};
            v2f wx = __builtin_elementwise_max(rbx - ltx, zero);
            v2f wy = __builtin_elementwise_max(rby - lty, zero);
            v2f inter = wx * wy;                       // v_pk_mul
            v2f iou = exact_div2(inter, (aA + aB) - inter);

            const float iou0 = iou.x, iou1 = iou.y;
            const int m0 = 2 * p, m1 = m0 + 1;
            // row: in-pair winner (strict > picks m1 -> first-m on tie),
            // then running best (strict > -> first-m across iters)
            float pv = fmaxf(iou0, iou1);
            int   pm = (iou1 > iou0) ? m1 : m0;
            if (pv > best_v) { best_v = pv; best_m = pm; }

            s_col[wv][2 * i + 0][lane] = iou0;         // ds_write2_b32
            s_col[wv][2 * i + 1][lane] = iou1;
        }
        // col chunk reduce: 4 lanes (parts) per box, 16 serial entries each
        float v = -1.0f; int tb = 0;
#pragma unroll
        for (int t = 0; t < 16; ++t) {                // ascending anchor
            float o = s_col[wv][bi][rbase + t];
            if (o > v) { v = o; tb = t; }             // strict > : smallest t
        }
        unsigned aidx = (unsigned)(abase + rbase + tb);
        u64 key = ((u64)__float_as_uint(v) << 32) | (u64)(unsigned)(~aidx);
        { u64 o = dpp_u64(key, 0xB1); if (o > key) key = o; }   // xor 1
        { u64 o = dpp_u64(key, 0x4E); if (o > key) key = o; }   // xor 2
        if (part == 0) s_ck[wv][c * 16 + bi] = key;
    }

    rowkey[(size_t)b * A_TOTAL + abase + lane] =
        ((u64)__float_as_uint(best_v) << 32) | (u64)(unsigned)best_m;

    __syncthreads();
    if (tid < NM) {
        u64 k = s_ck[0][tid];
        for (int w = 1; w < WPB; ++w) if (s_ck[w][tid] > k) k = s_ck[w][tid];
        atomicMax(&colfinal[b * NM + tid], k);
    }
}

// Streaming epilogue (R5-proven): per-block override window + score + gather.
__global__ __launch_bounds__(256) void epilogue_kernel(
    const float4* __restrict__ bboxes, const int* __restrict__ labels,
    const u64* __restrict__ colfinal, const u64* __restrict__ rowkey,
    float* __restrict__ out_scores, float4* __restrict__ out_matched) {
#pragma clang fp contract(off)
    const int b = blockIdx.y, tid = threadIdx.x;
    const int a0 = blockIdx.x * 256, a = a0 + tid;   // A_TOTAL == 168*256

    __shared__ float4 sbox[NM];
    __shared__ float  s_cm[NM];
    __shared__ int    s_lab[NM];
    __shared__ int    ovr[256];
    ovr[tid] = -1;

    int my_ca = -1;
    if (tid < NM) {
        u64 k = colfinal[b * NM + tid];
        s_cm[tid] = __uint_as_float((unsigned)(k >> 32));
        my_ca = ~((int)(unsigned)(k & 0xFFFFFFFFull));   // recover anchor idx
        sbox[tid]  = bboxes[b * NM + tid];
        s_lab[tid] = labels[b * NM + tid];
    }
    __syncthreads();
    if (tid < NM && my_ca >= a0 && my_ca < a0 + 256)
        atomicMax(&ovr[my_ca - a0], tid);                // later j wins == max j
    __syncthreads();

    u64 rk = rowkey[(size_t)b * A_TOTAL + a];
    float best = __uint_as_float((unsigned)(rk >> 32));
    int   bi   = (int)(rk & 0xFFFFFFFFull);

    int o = ovr[tid];
    if (o >= 0) { bi = o; best = s_cm[o]; }

    float denom = fmaxf(s_cm[bi], 0.3f);        // IOU_THR
    float val   = (best < 0.15f) ? 0.0f : best; // IOU_THR * 0.5
    float score = val / denom;
    if (s_lab[bi] <= 0) score = 0.0f;

    out_scores[(size_t)b * A_TOTAL + a]  = score;
    out_matched[(size_t)b * A_TOTAL + a] = sbox[bi];
}

extern "C" void kernel_launch(void* const* d_in, const int* in_sizes, int n_in,
                              void* d_out, int out_size, void* d_ws, size_t ws_size,
                              hipStream_t stream) {
    const int*    labels  = (const int*)d_in[0];     // [NB, NM] int32
    const float4* bboxes  = (const float4*)d_in[1];  // [NB, NM, 4] xyxy
    const float4* anchors = (const float4*)d_in[2];  // [A_TOTAL, 4] cxcywh

    float* out = (float*)d_out;                      // scores [NB,A], matched [NB,A,4]

    char* ws = (char*)d_ws;
    u64*   rowkey   = (u64*)ws;                      ws += (size_t)NB * A_TOTAL * 8;
    u64*   colfinal = (u64*)ws;                      ws += (size_t)NB * NM * 8;
    float* pairbox  = (float*)ws;

    prep_kernel<<<(NB * NM) / 256, 256, 0, stream>>>(bboxes, pairbox, colfinal);

    dim3 g(SPLIT, NB);
    fused_kernel<<<g, 256, 0, stream>>>(anchors, pairbox, rowkey, colfinal);
    epilogue_kernel<<<g, 256, 0, stream>>>(
        bboxes, labels, colfinal, rowkey,
        out, (float4*)(out + (size_t)NB * A_TOTAL));
}